// Round 6
// baseline (116.788 us; speedup 1.0000x reference)
//
#include <hip/hip_runtime.h>
#include <stdint.h>

// Problem constants (from reference): B=4, T=512, S=256, V=50257.
#define DIM_B 4
#define DIM_T 512
#define DIM_S 256
#define DIM_V 50257
#define HSZ   512          // per-row LDS hash slots (256 entries -> load factor 0.5)
#define HMSK  (HSZ - 1)

// Patch kernel v2: one block per output row (b,t).
//  1. LDS hash v -> sum(p) (open addressing; exact duplicate accumulation).
//  2. Scan occupied slots: entries in 16-float lines FULLY inside this row are
//     pushed to a compact line list; boundary-line entries (<=2 lines/row)
//     get plain 4B stores (deduped unique addresses -> race-free vs neighbors).
//  3. Compose each listed line in full: 4 lanes x 4 floats = 64B coalesced
//     store (zeros + hash values). Full-sector writes skip the write-allocate
//     fetch (vendor fill evidence: FETCH~30KB for 1.6GB written), removing the
//     ~60-120MB RMW traffic that made R5's patch cost ~30us.
// Duplicate lines in the list are benign: both groups store identical bytes.
// Bulk zeroing stays on hipMemsetAsync (vendor fill, 6.8 TB/s measured).
__global__ __launch_bounds__(256) void patch_kernel(
    const float* __restrict__ p_pos,   // [B, T, S]
    const int*   __restrict__ src,     // [B, S]  (int64 narrowed to int32)
    float*       __restrict__ out)     // [B, T, V]
{
    __shared__ int   hk[HSZ];
    __shared__ float hv[HSZ];
    __shared__ int   llist[256];       // <=1 push per occupied slot (<=256)
    __shared__ int   lcount;

    const int row = blockIdx.x;        // row = b*T + t
    const int b   = row >> 9;          // T = 512
    const int tid = threadIdx.x;       // s index (S == blockDim.x == 256)

    for (int i = tid; i < HSZ; i += 256) { hk[i] = -1; hv[i] = 0.0f; }
    if (tid == 0) lcount = 0;
    __syncthreads();

    // ---- 1. hash build ----
    {
        const int   v = src[b * DIM_S + tid];
        const float p = p_pos[(size_t)row * DIM_S + tid];
        int h = v & HMSK;
        while (true) {
            const int prev = atomicCAS(&hk[h], -1, v);
            if (prev == -1 || prev == v) { atomicAdd(&hv[h], p); break; }
            h = (h + 1) & HMSK;
        }
    }
    __syncthreads();

    const long long rb = (long long)row * DIM_V;          // row base elem idx
    // 16-float lines fully contained in [rb, rb+V)
    const long long l_start = (rb + 15) >> 4;
    const long long l_end   = ((rb + DIM_V) >> 4) - 1;

    // ---- 2. slot scan: push contained lines / 4B-store boundary entries ----
    for (int i = tid; i < HSZ; i += 256) {
        const int v = hk[i];
        if (v >= 0) {
            const long long e    = rb + v;
            const long long line = e >> 4;
            if (line >= l_start && line <= l_end) {
                const int idx = atomicAdd(&lcount, 1);
                llist[idx] = (int)(line - l_start);
            } else {
                out[e] = hv[i];        // boundary line: plain 4B store
            }
        }
    }
    __syncthreads();

    // ---- 3. compose full 64B lines, dense across all lanes ----
    const int nitems = lcount << 2;    // 4 quads per line
    for (int it = tid; it < nitems; it += 256) {
        const long long line = l_start + (long long)llist[it >> 2];
        const int       q    = it & 3;                     // quad in line
        const long long e0   = (line << 4) + (q << 2);     // first elem of quad
        float4 o;
        float* po = (float*)&o;
        #pragma unroll
        for (int j = 0; j < 4; ++j) {
            const int col = (int)(e0 + j - rb);            // in [0, V)
            int   h   = col & HMSK;
            float val = 0.0f;
            while (true) {
                const int k = hk[h];
                if (k == col) { val = hv[h]; break; }
                if (k == -1)  break;
                h = (h + 1) & HMSK;
            }
            po[j] = val;
        }
        *(float4*)(out + e0) = o;      // 16B-aligned, 4 lanes -> full 64B line
    }
}

extern "C" void kernel_launch(void* const* d_in, const int* in_sizes, int n_in,
                              void* d_out, int out_size, void* d_ws, size_t ws_size,
                              hipStream_t stream) {
    const float* p_pos = (const float*)d_in[0];   // [B,T,S]
    // d_in[1] = p_target_vocab — dead data (shape-only in the reference).
    const int*   src   = (const int*)d_in[2];     // [B,S]
    float*       out   = (float*)d_out;           // [B,T,V]

    // Bulk zero via the vendor fill path (graph-captures as a memset node).
    hipMemsetAsync(d_out, 0, (size_t)out_size * sizeof(float), stream);

    // Compose-and-store the scattered values as full 64B lines.
    patch_kernel<<<DIM_B * DIM_T, DIM_S, 0, stream>>>(p_pos, src, out);
}

// Round 7
// 88.667 us; speedup vs baseline: 1.3172x; 1.3172x over previous
//
#include <hip/hip_runtime.h>
#include <stdint.h>

// Problem constants (from reference): B=4, T=512, S=256, V=50257.
#define DIM_B 4
#define DIM_T 512
#define DIM_S 256
#define DIM_V 50257
#define DEPTH 4            // register patch slots per thread (Poisson(1): P(>4)~0.4%)

// Single-touch kernel: one block per output row (b,t).
// Phase 1 (route): each thread takes its raw (v, p) entry and pushes it into
//   the LDS bucket of the thread that will stream chunk c = (v-head)>>2
//   (owner t = c & 255). NO dedupe hash: duplicates become two additive
//   register patches. Head/tail elems and bucket overflow (>DEPTH) go to an
//   LDS overflow list.
// Phase 2 (stream): each thread streams its 50 float4 chunks with patches in
//   REGISTERS: 16 compare/selects + 1 store per iter. No loads, no branches,
//   no waitcnt in the loop (the R3/R4 killer). Every middle byte written once.
// Phase 3 (overflow): __syncthreads (drains vmcnt -> stores are in L2), then
//   apply overflow entries with global atomicAdd (executes at L2, same XCD,
//   all addresses row-local -> ordered, race-free).
__global__ __launch_bounds__(256) void onepass_kernel(
    const float* __restrict__ p_pos,   // [B, T, S]
    const int*   __restrict__ src,     // [B, S]  (int64 narrowed to int32)
    float*       __restrict__ out)     // [B, T, V]
{
    __shared__ uint32_t bkey[256][DEPTH];   // middle-local elem offset d
    __shared__ float    bval[256][DEPTH];
    __shared__ int      bcnt[256];
    __shared__ uint32_t okey[DIM_S];        // overflow: row-local elem v
    __shared__ float    oval[DIM_S];
    __shared__ int      ocnt;

    const int row = blockIdx.x;        // row = b*T + t
    const int b   = row >> 9;          // T = 512
    const int tid = threadIdx.x;       // s index (S == blockDim.x == 256)

    bcnt[tid] = 0;
    if (tid == 0) ocnt = 0;
    __syncthreads();

    const long long rb   = (long long)row * DIM_V;
    const int head  = (int)((4 - (row & 3)) & 3);   // 50257 % 4 == 1
    const int nvec  = (DIM_V - head) >> 2;          // 12563 or 12564 chunks
    const int ntail = DIM_V - head - (nvec << 2);   // 0..3

    // ---- Phase 1: route this thread's entry ----
    {
        const int   v = src[b * DIM_S + tid];
        const float p = p_pos[(size_t)row * DIM_S + tid];
        const int   d = v - head;                   // middle-local elem offset
        bool to_ovf = true;
        if (d >= 0 && d < (nvec << 2)) {
            const int c = d >> 2;                   // chunk index
            const int t = c & 255;                  // owning thread
            const int j = atomicAdd(&bcnt[t], 1);
            if (j < DEPTH) { bkey[t][j] = (uint32_t)d; bval[t][j] = p; to_ovf = false; }
        }
        if (to_ovf) {
            const int j = atomicAdd(&ocnt, 1);
            okey[j] = (uint32_t)v; oval[j] = p;
        }
    }
    __syncthreads();

    // ---- pull my register patches (sentinel never matches d <= 50255) ----
    uint32_t k0 = 0xFFFFFFFFu, k1 = 0xFFFFFFFFu, k2 = 0xFFFFFFFFu, k3 = 0xFFFFFFFFu;
    float    v0 = 0.0f, v1 = 0.0f, v2 = 0.0f, v3 = 0.0f;
    {
        const int cnt = bcnt[tid];                  // may exceed DEPTH
        if (cnt > 0) { k0 = bkey[tid][0]; v0 = bval[tid][0]; }
        if (cnt > 1) { k1 = bkey[tid][1]; v1 = bval[tid][1]; }
        if (cnt > 2) { k2 = bkey[tid][2]; v2 = bval[tid][2]; }
        if (cnt > 3) { k3 = bkey[tid][3]; v3 = bval[tid][3]; }
    }

    float* __restrict__ rowp = out + rb;

    // scalar head/tail (patched later by overflow atomics if targeted)
    if (tid < head)  rowp[tid] = 0.0f;
    if (tid < ntail) rowp[head + (nvec << 2) + tid] = 0.0f;

    // ---- Phase 2: pure-store stream with register compares ----
    float4* __restrict__ vp = (float4*)(rowp + head);
    #pragma unroll 2
    for (int c = tid; c < nvec; c += 256) {
        const uint32_t d0 = (uint32_t)(c << 2);
        float4 o;
        o.x = ((k0 == d0    ) ? v0 : 0.0f) + ((k1 == d0    ) ? v1 : 0.0f)
            + ((k2 == d0    ) ? v2 : 0.0f) + ((k3 == d0    ) ? v3 : 0.0f);
        o.y = ((k0 == d0 + 1) ? v0 : 0.0f) + ((k1 == d0 + 1) ? v1 : 0.0f)
            + ((k2 == d0 + 1) ? v2 : 0.0f) + ((k3 == d0 + 1) ? v3 : 0.0f);
        o.z = ((k0 == d0 + 2) ? v0 : 0.0f) + ((k1 == d0 + 2) ? v1 : 0.0f)
            + ((k2 == d0 + 2) ? v2 : 0.0f) + ((k3 == d0 + 2) ? v3 : 0.0f);
        o.w = ((k0 == d0 + 3) ? v0 : 0.0f) + ((k1 == d0 + 3) ? v1 : 0.0f)
            + ((k2 == d0 + 3) ? v2 : 0.0f) + ((k3 == d0 + 3) ? v3 : 0.0f);
        vp[c] = o;
    }

    // ---- Phase 3: overflow (barrier drains vmcnt; atomics execute at L2) ----
    __syncthreads();
    for (int i = tid; i < ocnt; i += 256) {
        atomicAdd(rowp + okey[i], oval[i]);
    }
}

extern "C" void kernel_launch(void* const* d_in, const int* in_sizes, int n_in,
                              void* d_out, int out_size, void* d_ws, size_t ws_size,
                              hipStream_t stream) {
    const float* p_pos = (const float*)d_in[0];   // [B,T,S]
    // d_in[1] = p_target_vocab — dead data (shape-only in the reference).
    const int*   src   = (const int*)d_in[2];     // [B,S]
    float*       out   = (float*)d_out;           // [B,T,V]

    onepass_kernel<<<DIM_B * DIM_T, DIM_S, 0, stream>>>(p_pos, src, out);
}